// Round 1
// baseline (25.358 us; speedup 1.0000x reference)
//
#include <hip/hip_runtime.h>

namespace {

constexpr int Dd = 6;
constexpr int Nn = 256;
constexpr int Rr = 16;
constexpr int W  = 20;   // word stride for Qt/Kt/Vt rows (16 data + 4 pad, 16B-aligned)
constexpr int PW = 20;   // word stride for score partials

__device__ __forceinline__ float fast_tanh(float xv) {
  // tanh(x) = (e^{2x}-1)/(e^{2x}+1); clamp avoids inf/inf NaN for |x|>44
  float xc = fminf(fmaxf(xv, -30.0f), 30.0f);
  float e  = __expf(2.0f * xc);
  return (e - 1.0f) * __builtin_amdgcn_rcpf(e + 1.0f);
}

__global__ __launch_bounds__(256) void att_h_fused(
    const float* __restrict__ x,   // [B, D, N]
    const float* __restrict__ L,   // [B, N, N] (only row 0 used)
    const float* __restrict__ Aq,  // [R, D]
    const float* __restrict__ Ak,  // [R, D]
    const float* __restrict__ Av,  // [R, D]
    const float* __restrict__ Ao,  // [1, R]
    float* __restrict__ out)       // [B, 1]
{
  __shared__ __align__(16) float Qt[Nn * W];     // Qt[n*W + r] = Q[r][n]
  __shared__ __align__(16) float Kt[Nn * W];
  __shared__ __align__(16) float Vt[Nn * W];
  __shared__ __align__(16) float part[4 * Rr * PW];  // [wave][tile][16]
  __shared__ float att[Rr * 17];                 // attn[r][s], stride 17
  __shared__ __align__(16) float wsh[Rr];        // w[s] = sum_r Ao[r]*attn[r][s]
  __shared__ float red[4];

  const int b    = blockIdx.x;
  const int tid  = threadIdx.x;
  const int wave = tid >> 6;
  const int lane = tid & 63;

  // ---- numNeighbors: count(L[b,0,n] >= 1) + 1
  const float lv = L[(size_t)b * Nn * Nn + tid];
  const unsigned long long bal = __ballot(lv >= 1.0f);
  if (lane == 0) red[wave] = (float)__popcll(bal);

  // ---- x column for n = tid (coalesced across threads per d)
  const float* xb = x + (size_t)b * Dd * Nn;
  float xr[Dd];
#pragma unroll
  for (int d = 0; d < Dd; ++d) xr[d] = xb[d * Nn + tid];

  __syncthreads();
  const float scale = rsqrtf(red[0] + red[1] + red[2] + red[3] + 1.0f);

  // ---- Q/K/V projections + tanh. A* reads are wave-uniform -> scalar loads.
  float q[Rr], k[Rr], v[Rr];
#pragma unroll
  for (int r = 0; r < Rr; ++r) {
    float aq = 0.0f, ak = 0.0f, av = 0.0f;
#pragma unroll
    for (int d = 0; d < Dd; ++d) {
      aq = fmaf(Aq[r * Dd + d], xr[d], aq);
      ak = fmaf(Ak[r * Dd + d], xr[d], ak);
      av = fmaf(Av[r * Dd + d], xr[d], av);
    }
    q[r] = fast_tanh(aq);
    k[r] = fast_tanh(ak);
    v[r] = fast_tanh(av);
  }
  // transposed float4 stores; stride 20 words -> 8-way bank-group spread, conflict-free
#pragma unroll
  for (int cg = 0; cg < 4; ++cg) {
    *(float4*)&Qt[tid * W + 4 * cg] =
        make_float4(q[4 * cg], q[4 * cg + 1], q[4 * cg + 2], q[4 * cg + 3]);
    *(float4*)&Kt[tid * W + 4 * cg] =
        make_float4(k[4 * cg], k[4 * cg + 1], k[4 * cg + 2], k[4 * cg + 3]);
    *(float4*)&Vt[tid * W + 4 * cg] =
        make_float4(v[4 * cg], v[4 * cg + 1], v[4 * cg + 2], v[4 * cg + 3]);
  }
  __syncthreads();

  // ---- scores[r][s] = sum_n Q[r][n]*K[s][n] : 4x4 register tile per lane,
  //      each wave covers one n-quarter; lane = (nsub<<4) | tile
  {
    const int tile = lane & 15;
    const int rt   = tile >> 2;
    const int st   = tile & 3;
    const int nsub = lane >> 4;
    const int nbase = wave * 64 + nsub;

    float acc[4][4] = {};
#pragma unroll
    for (int i = 0; i < 16; ++i) {
      const int n = nbase + i * 4;
      const float4 qv = *(const float4*)&Qt[n * W + 4 * rt];
      const float4 kv = *(const float4*)&Kt[n * W + 4 * st];
      acc[0][0] = fmaf(qv.x, kv.x, acc[0][0]);
      acc[0][1] = fmaf(qv.x, kv.y, acc[0][1]);
      acc[0][2] = fmaf(qv.x, kv.z, acc[0][2]);
      acc[0][3] = fmaf(qv.x, kv.w, acc[0][3]);
      acc[1][0] = fmaf(qv.y, kv.x, acc[1][0]);
      acc[1][1] = fmaf(qv.y, kv.y, acc[1][1]);
      acc[1][2] = fmaf(qv.y, kv.z, acc[1][2]);
      acc[1][3] = fmaf(qv.y, kv.w, acc[1][3]);
      acc[2][0] = fmaf(qv.z, kv.x, acc[2][0]);
      acc[2][1] = fmaf(qv.z, kv.y, acc[2][1]);
      acc[2][2] = fmaf(qv.z, kv.z, acc[2][2]);
      acc[2][3] = fmaf(qv.z, kv.w, acc[2][3]);
      acc[3][0] = fmaf(qv.w, kv.x, acc[3][0]);
      acc[3][1] = fmaf(qv.w, kv.y, acc[3][1]);
      acc[3][2] = fmaf(qv.w, kv.z, acc[3][2]);
      acc[3][3] = fmaf(qv.w, kv.w, acc[3][3]);
    }
    // reduce over nsub (lane bits 4,5)
#pragma unroll
    for (int a = 0; a < 4; ++a) {
#pragma unroll
      for (int c = 0; c < 4; ++c) {
        float t = acc[a][c];
        t += __shfl_xor(t, 16);
        t += __shfl_xor(t, 32);
        acc[a][c] = t;
      }
    }
    if (lane < 16) {
#pragma unroll
      for (int a = 0; a < 4; ++a) {
        *(float4*)&part[(wave * Rr + tile) * PW + 4 * a] =
            make_float4(acc[a][0], acc[a][1], acc[a][2], acc[a][3]);
      }
    }
  }
  __syncthreads();

  // ---- softmax over s (one score element per thread), then w[s] = Ao . attn[:,s]
  {
    const int r  = tid >> 4;
    const int s  = tid & 15;
    const int tl = (r >> 2) * 4 + (s >> 2);
    const int ix = (r & 3) * 4 + (s & 3);
    float sc = 0.0f;
#pragma unroll
    for (int wv = 0; wv < 4; ++wv) sc += part[(wv * Rr + tl) * PW + ix];
    sc *= scale;

    float mx = sc;
#pragma unroll
    for (int off = 1; off < 16; off <<= 1) mx = fmaxf(mx, __shfl_xor(mx, off));
    const float e = __expf(sc - mx);
    float sm = e;
#pragma unroll
    for (int off = 1; off < 16; off <<= 1) sm += __shfl_xor(sm, off);
    att[r * 17 + s] = e * __builtin_amdgcn_rcpf(sm);
  }
  __syncthreads();

  if (tid < Rr) {
    float w = 0.0f;
#pragma unroll
    for (int r2 = 0; r2 < Rr; ++r2) w = fmaf(Ao[r2], att[r2 * 17 + tid], w);
    wsh[tid] = w;
  }
  __syncthreads();

  // ---- H[n] = silu(sum_s w[s] * V[s][n]), then block-sum and square
  float h = 0.0f;
#pragma unroll
  for (int cg = 0; cg < 4; ++cg) {
    const float4 wv = *(const float4*)&wsh[4 * cg];
    const float4 vv = *(const float4*)&Vt[tid * W + 4 * cg];
    h = fmaf(wv.x, vv.x, h);
    h = fmaf(wv.y, vv.y, h);
    h = fmaf(wv.z, vv.z, h);
    h = fmaf(wv.w, vv.w, h);
  }
  const float Hv = h * __builtin_amdgcn_rcpf(1.0f + __expf(-h));

  float t = Hv;
#pragma unroll
  for (int off = 1; off < 64; off <<= 1) t += __shfl_xor(t, off);
  if (lane == 0) red[wave] = t;  // red last read long ago (>=3 barriers): safe reuse
  __syncthreads();
  if (tid == 0) {
    const float tot = red[0] + red[1] + red[2] + red[3];
    out[b] = tot * tot;
  }
}

}  // namespace

extern "C" void kernel_launch(void* const* d_in, const int* in_sizes, int n_in,
                              void* d_out, int out_size, void* d_ws, size_t ws_size,
                              hipStream_t stream) {
  const float* x  = (const float*)d_in[0];
  const float* L  = (const float*)d_in[1];
  const float* Aq = (const float*)d_in[2];
  const float* Ak = (const float*)d_in[3];
  const float* Av = (const float*)d_in[4];
  const float* Ao = (const float*)d_in[5];
  float* out = (float*)d_out;

  const int B = in_sizes[0] / (Dd * Nn);  // 2048
  att_h_fused<<<dim3(B), dim3(256), 0, stream>>>(x, L, Aq, Ak, Av, Ao, out);
}

// Round 2
// 17.024 us; speedup vs baseline: 1.4896x; 1.4896x over previous
//
#include <hip/hip_runtime.h>

namespace {

constexpr int Dd   = 6;
constexpr int Nn   = 256;
constexpr int Rr   = 16;
constexpr int QSTR = 264;  // ushort stride per row: 256 data + 8 pad = 528 B (33*16B, odd*16 -> 2-way banks)

typedef __attribute__((ext_vector_type(8))) short bf16x8;
typedef __attribute__((ext_vector_type(4))) float f32x4;

// tanh(x) = 1 - 2/(exp2(2x*log2e)+1). No clamp needed: x->+inf gives e=inf,
// rcp(inf)=0 -> 1; x->-inf gives e=0 -> -1. 3 VALU + 2 trans.
__device__ __forceinline__ float fast_tanh(float xv) {
  float e = __builtin_amdgcn_exp2f(xv * 2.8853900817779268f);
  return fmaf(-2.0f, __builtin_amdgcn_rcpf(e + 1.0f), 1.0f);
}

// f32 pair -> packed bf16 with RNE (no builtin on gfx950; guide T12 recipe)
__device__ __forceinline__ unsigned pack_bf16(float a, float b) {
  unsigned r;
  asm("v_cvt_pk_bf16_f32 %0, %1, %2" : "=v"(r) : "v"(a), "v"(b));
  return r;
}

__global__ __launch_bounds__(256) void att_h_fused(
    const float* __restrict__ x,   // [B, D, N]
    const float* __restrict__ L,   // [B, N, N] (only row 0 used)
    const float* __restrict__ Aq,  // [R, D]
    const float* __restrict__ Ak,  // [R, D]
    const float* __restrict__ Av,  // [R, D]
    const float* __restrict__ Ao,  // [1, R]
    float* __restrict__ out)       // [B, 1]
{
  // bf16 row-major [r][n] panels for MFMA operand reads (16B/lane, b128)
  __shared__ __align__(16) unsigned short Qb[Rr * QSTR];  // 8448 B
  __shared__ __align__(16) unsigned short Kb[Rr * QSTR];  // 8448 B
  __shared__ __align__(16) float wsh[Rr];                 // w[s] broadcast
  __shared__ float red[4];

  const int b    = blockIdx.x;
  const int tid  = threadIdx.x;
  const int wave = tid >> 6;
  const int lane = tid & 63;

  // ---- numNeighbors: count(L[b,0,n] >= 1) + 1
  const float lv = L[(size_t)b * Nn * Nn + tid];
  const unsigned long long bal = __ballot(lv >= 1.0f);
  if (lane == 0) red[wave] = (float)__popcll(bal);

  // ---- x column for n = tid (coalesced per d)
  const float* xb = x + (size_t)b * Dd * Nn;
  float xr[Dd];
#pragma unroll
  for (int d = 0; d < Dd; ++d) xr[d] = xb[d * Nn + tid];

  // ---- Q/K/V projections + tanh. A* reads are wave-uniform -> s_load.
  float q[Rr], k[Rr], v[Rr];
#pragma unroll
  for (int r = 0; r < Rr; ++r) {
    float aq = 0.0f, ak = 0.0f, av = 0.0f;
#pragma unroll
    for (int d = 0; d < Dd; ++d) {
      aq = fmaf(Aq[r * Dd + d], xr[d], aq);
      ak = fmaf(Ak[r * Dd + d], xr[d], ak);
      av = fmaf(Av[r * Dd + d], xr[d], av);
    }
    q[r] = fast_tanh(aq);
    k[r] = fast_tanh(ak);
    v[r] = fast_tanh(av);   // stays in registers; consumed in H phase
  }

  // ---- pack Q,K to bf16 and scatter to [r][n=tid] (ds_write_b16; 2 lanes/word = free 2-way)
#pragma unroll
  for (int j = 0; j < 8; ++j) {
    const unsigned pq = pack_bf16(q[2 * j], q[2 * j + 1]);
    const unsigned pk = pack_bf16(k[2 * j], k[2 * j + 1]);
    Qb[(2 * j) * QSTR + tid]     = (unsigned short)pq;
    Qb[(2 * j + 1) * QSTR + tid] = (unsigned short)(pq >> 16);
    Kb[(2 * j) * QSTR + tid]     = (unsigned short)pk;
    Kb[(2 * j + 1) * QSTR + tid] = (unsigned short)(pk >> 16);
  }
  __syncthreads();  // covers red[] and Qb/Kb

  // ---- wave 0: scores via 8x mfma_f32_16x16x32_bf16 (K=256), softmax, w[s]
  if (wave == 0) {
    const float scale = rsqrtf(red[0] + red[1] + red[2] + red[3] + 1.0f);
    const int col = lane & 15;   // A: row r = col ; B: row s = col
    const int hi  = lane >> 4;   // k-group
    const int off = hi * 8;      // 8 contiguous n per lane

    f32x4 acc = {0.0f, 0.0f, 0.0f, 0.0f};
#pragma unroll
    for (int blk = 0; blk < 8; ++blk) {
      const bf16x8 af = *(const bf16x8*)&Qb[col * QSTR + blk * 32 + off];
      const bf16x8 bf = *(const bf16x8*)&Kb[col * QSTR + blk * 32 + off];
      acc = __builtin_amdgcn_mfma_f32_16x16x32_bf16(af, bf, acc, 0, 0, 0);
    }
    // C/D layout: s = lane&15, r = (lane>>4)*4 + reg  [m89-verified]
    float att[4];
#pragma unroll
    for (int j = 0; j < 4; ++j) {
      const float sc = acc[j] * scale;
      float mj = sc;
#pragma unroll
      for (int o = 1; o < 16; o <<= 1) mj = fmaxf(mj, __shfl_xor(mj, o));
      const float ej = __builtin_amdgcn_exp2f((sc - mj) * 1.4426950408889634f);
      float sj = ej;
#pragma unroll
      for (int o = 1; o < 16; o <<= 1) sj += __shfl_xor(sj, o);
      att[j] = ej * __builtin_amdgcn_rcpf(sj);
    }
    // w[s] = sum_r Ao[r] * attn[r][s];  r = hi*4 + j
    const float4 ao4 = *(const float4*)(Ao + hi * 4);
    float wp = 0.0f;
    wp = fmaf(ao4.x, att[0], wp);
    wp = fmaf(ao4.y, att[1], wp);
    wp = fmaf(ao4.z, att[2], wp);
    wp = fmaf(ao4.w, att[3], wp);
    wp += __shfl_xor(wp, 16);
    wp += __shfl_xor(wp, 32);
    if (lane < Rr) wsh[lane] = wp;
  }
  __syncthreads();

  // ---- H[n] = silu(sum_s w[s] * v[s]) with v in registers; block-sum; square
  float h = 0.0f;
#pragma unroll
  for (int cg = 0; cg < 4; ++cg) {
    const float4 wv = *(const float4*)&wsh[4 * cg];
    h = fmaf(wv.x, v[4 * cg + 0], h);
    h = fmaf(wv.y, v[4 * cg + 1], h);
    h = fmaf(wv.z, v[4 * cg + 2], h);
    h = fmaf(wv.w, v[4 * cg + 3], h);
  }
  const float e  = __builtin_amdgcn_exp2f(-1.4426950408889634f * h);
  const float Hv = h * __builtin_amdgcn_rcpf(1.0f + e);

  float t = Hv;
#pragma unroll
  for (int o = 1; o < 64; o <<= 1) t += __shfl_xor(t, o);
  if (lane == 0) red[wave] = t;  // safe: all reads of red happened before barrier 2
  __syncthreads();
  if (tid == 0) {
    const float tot = red[0] + red[1] + red[2] + red[3];
    out[b] = tot * tot;
  }
}

}  // namespace

extern "C" void kernel_launch(void* const* d_in, const int* in_sizes, int n_in,
                              void* d_out, int out_size, void* d_ws, size_t ws_size,
                              hipStream_t stream) {
  const float* x  = (const float*)d_in[0];
  const float* L  = (const float*)d_in[1];
  const float* Aq = (const float*)d_in[2];
  const float* Ak = (const float*)d_in[3];
  const float* Av = (const float*)d_in[4];
  const float* Ao = (const float*)d_in[5];
  float* out = (float*)d_out;

  const int B = in_sizes[0] / (Dd * Nn);  // 2048
  att_h_fused<<<dim3(B), dim3(256), 0, stream>>>(x, L, Aq, Ak, Av, Ao, out);
}